// Round 1
// baseline (20729.585 us; speedup 1.0000x reference)
//
#include <hip/hip_runtime.h>
#include <cstdint>

#define Bb 256
#define Tt 512
#define Dd 128
#define Hh 512
#define BH (Bb*Hh)            // 131072
#define KGATE 640
#define NCT (Hh/16)           // 32 col-tiles per matrix
#define MATSZ (KGATE*Hh)      // 327680 elements per gate matrix
#define WA_OFF (8*MATSZ)      // 2621440

typedef unsigned short ushort_t;
typedef __bf16 bf16x8 __attribute__((ext_vector_type(8)));
typedef unsigned short u16x8 __attribute__((ext_vector_type(8)));
typedef float f32x4 __attribute__((ext_vector_type(4)));

static __device__ inline ushort_t f2bf(float f){
    union { float f; uint32_t u; } v; v.f = f;
    uint32_t u = v.u;
    uint32_t r = (u + 0x7FFFu + ((u >> 16) & 1u)) >> 16;
    return (ushort_t)r;
}
static __device__ inline float sigmoidf_(float x){ return 1.f/(1.f+__expf(-x)); }
static __device__ inline float tanhf_(float x){
    float ax = fabsf(x);
    float t = __expf(-2.f*ax);
    float r = (1.f - t)/(1.f + t);
    return copysignf(r, x);
}

// Pack one weight matrix (optionally stacked [W(128 rows); U(512 rows)]) into
// MFMA B-fragment order: elem(lane,j) = M[kb*32 + (lane>>4)*8 + j][ct*16 + (lane&15)]
__global__ void pack_mat(const float* __restrict__ Wm, const float* __restrict__ Um,
                         int Ktot, ushort_t* __restrict__ dst){
    int total = Ktot * 64;  // groups of 8 bf16
    for (int g = blockIdx.x*blockDim.x + threadIdx.x; g < total; g += gridDim.x*blockDim.x){
        int kb   = g >> 11;        // / (32*64)
        int rem  = g & 2047;
        int ct   = rem >> 6;
        int lane = rem & 63;
        int k0   = kb*32 + ((lane >> 4) << 3);
        int col  = (ct << 4) + (lane & 15);
        u16x8 o8;
        #pragma unroll
        for (int j = 0; j < 8; ++j){
            int k = k0 + j;
            float v;
            if (Um) v = (k < Dd) ? Wm[k*Hh + col] : Um[(k - Dd)*Hh + col];
            else    v = Wm[k*Hh + col];
            o8[j] = f2bf(v);
        }
        *reinterpret_cast<u16x8*>(dst + (size_t)g*8) = o8;
    }
}

__global__ void init_state(ushort_t* hbf, float* c){
    int i = blockIdx.x*blockDim.x + threadIdx.x;
    if (i < BH){ hbf[i] = 0; c[i] = 0.f; }
}

struct GateArgs {
    const ushort_t* wpack; const ushort_t* hbf;
    const float* X[3];         // Y, P, N
    const float* bC[3];        // b_c, b_c_p, b_c_n
    const float* bI[3];        // b_i, b_i_p, b_i_n
    const float* bF; const float* bO;
    ushort_t* l_bf; float* l_f; float* fo_f;
    int t;
};

// grid: (8 col-tiles, 4 row-tiles, 5 units); block 256.
// unit 0..2: l_t/l_p/l_n (two matrices: c-mat + i-mat); unit 3: f; unit 4: o.
__global__ __launch_bounds__(256) void gates_kernel(GateArgs A){
    const int u = blockIdx.z;
    const int lane = threadIdx.x & 63;
    const int wave = threadIdx.x >> 6;
    const int rowbase = blockIdx.y*64 + (wave & 1)*32;
    const int colbase = blockIdx.x*64 + (wave >> 1)*32;

    const float* Xs; int mat0, mat1; const float* bias0; const float* bias1 = nullptr;
    if (u < 3){ Xs = A.X[u]; mat0 = 4 + u; mat1 = u; bias0 = A.bC[u]; bias1 = A.bI[u]; }
    else if (u == 3){ Xs = A.X[0]; mat0 = 3; mat1 = -1; bias0 = A.bF; }
    else            { Xs = A.X[0]; mat0 = 7; mat1 = -1; bias0 = A.bO; }

    const ushort_t* wp0 = A.wpack + (size_t)mat0*MATSZ;
    const ushort_t* wp1 = (mat1 >= 0) ? (A.wpack + (size_t)mat1*MATSZ) : nullptr;

    f32x4 acc0[2][2] = {{{0.f,0.f,0.f,0.f},{0.f,0.f,0.f,0.f}},{{0.f,0.f,0.f,0.f},{0.f,0.f,0.f,0.f}}};
    f32x4 acc1[2][2] = {{{0.f,0.f,0.f,0.f},{0.f,0.f,0.f,0.f}},{{0.f,0.f,0.f,0.f},{0.f,0.f,0.f,0.f}}};
    const int r15 = lane & 15;
    const int khi = (lane >> 4) << 3;
    const int t_ = A.t;

    for (int kb = 0; kb < KGATE/32; ++kb){
        int k0 = kb*32 + khi;
        bf16x8 a[2];
        if (kb < 4){
            #pragma unroll
            for (int fi = 0; fi < 2; ++fi){
                int arow = rowbase + fi*16 + r15;
                const float* xp = Xs + ((size_t)arow*Tt + t_)*Dd + k0;
                f32x4 v0 = *reinterpret_cast<const f32x4*>(xp);
                f32x4 v1 = *reinterpret_cast<const f32x4*>(xp + 4);
                u16x8 tmp;
                #pragma unroll
                for (int j = 0; j < 4; ++j){ tmp[j] = f2bf(v0[j]); tmp[4+j] = f2bf(v1[j]); }
                a[fi] = __builtin_bit_cast(bf16x8, tmp);
            }
        } else {
            #pragma unroll
            for (int fi = 0; fi < 2; ++fi){
                int arow = rowbase + fi*16 + r15;
                a[fi] = *reinterpret_cast<const bf16x8*>(A.hbf + (size_t)arow*Hh + (k0 - Dd));
            }
        }
        #pragma unroll
        for (int fj = 0; fj < 2; ++fj){
            int ct = (colbase + fj*16) >> 4;
            size_t bidx = ((size_t)(kb*NCT + ct)*64 + lane)*8;
            bf16x8 b0 = *reinterpret_cast<const bf16x8*>(wp0 + bidx);
            #pragma unroll
            for (int fi = 0; fi < 2; ++fi)
                acc0[fi][fj] = __builtin_amdgcn_mfma_f32_16x16x32_bf16(a[fi], b0, acc0[fi][fj], 0, 0, 0);
            if (wp1){
                bf16x8 b1 = *reinterpret_cast<const bf16x8*>(wp1 + bidx);
                #pragma unroll
                for (int fi = 0; fi < 2; ++fi)
                    acc1[fi][fj] = __builtin_amdgcn_mfma_f32_16x16x32_bf16(a[fi], b1, acc1[fi][fj], 0, 0, 0);
            }
        }
    }

    #pragma unroll
    for (int fi = 0; fi < 2; ++fi)
    #pragma unroll
    for (int fj = 0; fj < 2; ++fj)
    #pragma unroll
    for (int r = 0; r < 4; ++r){
        int brow = rowbase + fi*16 + ((lane >> 4) << 2) + r;
        int col  = colbase + fj*16 + r15;
        size_t idx = (size_t)brow*Hh + col;
        float g0 = acc0[fi][fj][r] + bias0[col];
        if (u < 3){
            float g1 = acc1[fi][fj][r] + bias1[col];
            float l = tanhf_(g0) * sigmoidf_(g1);
            A.l_f[(size_t)u*BH + idx]  = l;
            A.l_bf[(size_t)u*BH + idx] = f2bf(l);
        } else if (u == 3){
            A.fo_f[idx] = sigmoidf_(g0);
        } else {
            A.fo_f[(size_t)BH + idx] = sigmoidf_(g0);
        }
    }
}

struct UpdArgs {
    const ushort_t* wpack; const ushort_t* l_bf; const float* l_f;
    const float* fo_f; const float* b_a;
    float* c; ushort_t* hbf; float* out; int t;
};

// grid: (8 col-tiles, 4 row-tiles); block 256.
__global__ __launch_bounds__(256) void update_kernel(UpdArgs A){
    const int lane = threadIdx.x & 63;
    const int wave = threadIdx.x >> 6;
    const int rowbase = blockIdx.y*64 + (wave & 1)*32;
    const int colbase = blockIdx.x*64 + (wave >> 1)*32;
    const int r15 = lane & 15;
    const int khi = (lane >> 4) << 3;
    const ushort_t* wa = A.wpack + (size_t)WA_OFF;

    f32x4 acc[3][2][2];
    #pragma unroll
    for (int s = 0; s < 3; ++s)
        #pragma unroll
        for (int fi = 0; fi < 2; ++fi)
            #pragma unroll
            for (int fj = 0; fj < 2; ++fj)
                acc[s][fi][fj] = f32x4{0.f,0.f,0.f,0.f};

    for (int kb = 0; kb < Hh/32; ++kb){
        int k0 = kb*32 + khi;
        bf16x8 a[3][2];
        #pragma unroll
        for (int s = 0; s < 3; ++s)
            #pragma unroll
            for (int fi = 0; fi < 2; ++fi){
                int arow = rowbase + fi*16 + r15;
                a[s][fi] = *reinterpret_cast<const bf16x8*>(A.l_bf + (size_t)s*BH + (size_t)arow*Hh + k0);
            }
        #pragma unroll
        for (int fj = 0; fj < 2; ++fj){
            int ct = (colbase + fj*16) >> 4;
            size_t bidx = ((size_t)(kb*NCT + ct)*64 + lane)*8;
            bf16x8 b = *reinterpret_cast<const bf16x8*>(wa + bidx);
            #pragma unroll
            for (int s = 0; s < 3; ++s)
                #pragma unroll
                for (int fi = 0; fi < 2; ++fi)
                    acc[s][fi][fj] = __builtin_amdgcn_mfma_f32_16x16x32_bf16(a[s][fi], b, acc[s][fi][fj], 0, 0, 0);
        }
    }

    const int t_ = A.t;
    #pragma unroll
    for (int fi = 0; fi < 2; ++fi)
    #pragma unroll
    for (int fj = 0; fj < 2; ++fj)
    #pragma unroll
    for (int r = 0; r < 4; ++r){
        int brow = rowbase + fi*16 + ((lane >> 4) << 2) + r;
        int col  = colbase + fj*16 + r15;
        size_t idx = (size_t)brow*Hh + col;
        float cv = A.c[idx];
        float ba = A.b_a[col];
        float e0 = __expf(tanhf_(acc[0][fi][fj][r]*cv + ba));
        float e1 = __expf(tanhf_(acc[1][fi][fj][r]*cv + ba));
        float e2 = __expf(tanhf_(acc[2][fi][fj][r]*cv + ba));
        float inv = 1.f/(e0 + e1 + e2);
        float L = (e0*A.l_f[idx] + e1*A.l_f[(size_t)BH + idx] + e2*A.l_f[(size_t)2*BH + idx])*inv;
        float f = A.fo_f[idx];
        float o = A.fo_f[(size_t)BH + idx];
        float cn = f*cv + L;
        A.c[idx] = cn;
        float hn = o * tanhf_(cn);
        A.hbf[idx] = f2bf(hn);
        A.out[(size_t)BH + ((size_t)brow*Tt + t_)*Hh + col] = hn;   // hidden_seq[b][t][h]
        if (t_ == Tt-1) A.out[(size_t)brow*Hh + col] = hn;          // h_last[b][h]
    }
}

extern "C" void kernel_launch(void* const* d_in, const int* in_sizes, int n_in,
                              void* d_out, int out_size, void* d_ws, size_t ws_size,
                              hipStream_t stream){
    const float* in[29];
    for (int i = 0; i < 29; ++i) in[i] = (const float*)d_in[i];

    char* ws = (char*)d_ws;
    ushort_t* wpack = (ushort_t*)(ws + 0);         // 5,767,168 B
    ushort_t* hbf   = (ushort_t*)(ws + 5767168);   //   262,144 B
    float*    cbuf  = (float*)   (ws + 6029312);   //   524,288 B
    ushort_t* l_bf  = (ushort_t*)(ws + 6553600);   //   786,432 B
    float*    l_f   = (float*)   (ws + 7340032);   // 1,572,864 B
    float*    fo_f  = (float*)   (ws + 8912896);   // 1,048,576 B
    // total ~9.96 MB of d_ws

    // mats: 0:i 1:i_p 2:i_n 3:f 4:c 5:c_p 6:c_n 7:o (K=640, [W;U]) ; 8: W_a (K=512)
    static const int WI[9] = {0, 3, 6, 9, 12, 15, 18, 21, 24};
    static const int UI[9] = {1, 4, 7, 10, 13, 16, 19, 22, -1};
    for (int m = 0; m < 9; ++m){
        int Ktot = (m == 8) ? Hh : KGATE;
        const float* Um = (m == 8) ? nullptr : in[UI[m]];
        int groups = Ktot*64;
        pack_mat<<<dim3((groups + 255)/256), dim3(256), 0, stream>>>(
            in[WI[m]], Um, Ktot, wpack + (size_t)m*MATSZ);
    }
    init_state<<<dim3(BH/256), dim3(256), 0, stream>>>(hbf, cbuf);

    GateArgs GA;
    GA.wpack = wpack; GA.hbf = hbf;
    GA.X[0] = in[26]; GA.X[1] = in[27]; GA.X[2] = in[28];
    GA.bC[0] = in[14]; GA.bC[1] = in[17]; GA.bC[2] = in[20];
    GA.bI[0] = in[2];  GA.bI[1] = in[5];  GA.bI[2] = in[8];
    GA.bF = in[11]; GA.bO = in[23];
    GA.l_bf = l_bf; GA.l_f = l_f; GA.fo_f = fo_f;

    UpdArgs UA;
    UA.wpack = wpack; UA.l_bf = l_bf; UA.l_f = l_f; UA.fo_f = fo_f;
    UA.b_a = in[25]; UA.c = cbuf; UA.hbf = hbf; UA.out = (float*)d_out;

    for (int t = 0; t < Tt; ++t){
        GA.t = t;
        gates_kernel<<<dim3(8, 4, 5), dim3(256), 0, stream>>>(GA);
        UA.t = t;
        update_kernel<<<dim3(8, 4, 1), dim3(256), 0, stream>>>(UA);
    }
}